// Round 1
// baseline (661.089 us; speedup 1.0000x reference)
//
#include <hip/hip_runtime.h>

#define E 100

__device__ __forceinline__ void dot25(const float* __restrict__ s,
                                      const float4* __restrict__ w4,
                                      float& acc) {
  #pragma unroll
  for (int q = 0; q < 25; ++q) {
    float4 w = w4[q];
    acc = fmaf(s[4*q+0], w.x, acc);
    acc = fmaf(s[4*q+1], w.y, acc);
    acc = fmaf(s[4*q+2], w.z, acc);
    acc = fmaf(s[4*q+3], w.w, acc);
  }
}

// Fused: leaf embedding gather + leaf projections + level-1 combine + level-1 proj.
// SPLIT=2: thread k in {0,1} per node; each computes 50 of the 100 outputs.
__global__ __launch_bounds__(256) void leaf_l1_kernel(
    const int* __restrict__ word_ids, const float* __restrict__ emb,
    const float* __restrict__ Wl, const float* __restrict__ bl,
    const float* __restrict__ Wp, const float* __restrict__ bp,
    float* __restrict__ h1, float* __restrict__ out) {
  int gt = blockIdx.x * blockDim.x + threadIdx.x;   // 131072 threads
  int node = gt >> 1;
  int k = gt & 1;
  int wi0 = word_ids[2*node];
  int wi1 = word_ids[2*node + 1];
  const float4* A4 = (const float4*)(emb + (size_t)wi0 * E);
  const float4* B4 = (const float4*)(emb + (size_t)wi1 * E);
  float s[E];
  float lp0 = bp[0], lp1 = bp[1];   // this thread's own leaf projection
  #pragma unroll
  for (int q = 0; q < 25; ++q) {
    float4 a = A4[q], b = B4[q];
    s[4*q+0] = a.x + b.x;
    s[4*q+1] = a.y + b.y;
    s[4*q+2] = a.z + b.z;
    s[4*q+3] = a.w + b.w;
    float4 m = k ? b : a;
    lp0 = fmaf(m.x, Wp[4*q+0], lp0);
    lp0 = fmaf(m.y, Wp[4*q+1], lp0);
    lp0 = fmaf(m.z, Wp[4*q+2], lp0);
    lp0 = fmaf(m.w, Wp[4*q+3], lp0);
    lp1 = fmaf(m.x, Wp[E+4*q+0], lp1);
    lp1 = fmaf(m.y, Wp[E+4*q+1], lp1);
    lp1 = fmaf(m.z, Wp[E+4*q+2], lp1);
    lp1 = fmaf(m.w, Wp[E+4*q+3], lp1);
  }
  // leaf output: level 0, leaf index li -> pos = 2*li - popc(li)
  int li = 2*node + k;
  int posl = 2*li - __popc(li);
  out[2*posl]   = lp0;
  out[2*posl+1] = lp1;
  // level-1 combine: e' in [k*50, k*50+50)
  float pj0 = 0.0f, pj1 = 0.0f;
  #pragma unroll 1
  for (int r = 0; r < 50; ++r) {
    int ep = k * 50 + r;
    float acc = 2.0f * bl[ep];
    dot25(s, (const float4*)(Wl + ep * E), acc);
    float o = fmaxf(acc, 0.0f);
    h1[(size_t)node * E + ep] = o;
    pj0 = fmaf(o, Wp[ep], pj0);
    pj1 = fmaf(o, Wp[E + ep], pj1);
  }
  pj0 += __shfl_xor(pj0, 1, 64);
  pj1 += __shfl_xor(pj1, 1, 64);
  if (k == 0) {
    int pos = ((node + 1) << 2) - 2 - __popc(node);   // level 1
    out[2*pos]   = pj0 + bp[0];
    out[2*pos+1] = pj1 + bp[1];
  }
}

// Generic level combine for levels 2..11. SPLIT lanes per node share the
// 100 outputs; projection partials reduced by shuffle.
template<int SPLIT>
__global__ __launch_bounds__(256) void combine_kernel(
    const float* __restrict__ hsrc, float* __restrict__ hdst,
    const float* __restrict__ Wl, const float* __restrict__ bl,
    const float* __restrict__ Wp, const float* __restrict__ bp,
    float* __restrict__ out, int n, int lvl) {
  constexpr int EPT = (E + SPLIT - 1) / SPLIT;
  int gt = blockIdx.x * blockDim.x + threadIdx.x;
  int node = gt / SPLIT;
  int k = gt % SPLIT;
  if (node >= n) return;
  float s[E];
  const float4* L4 = (const float4*)(hsrc + (size_t)node * (2 * E));
  #pragma unroll
  for (int q = 0; q < 25; ++q) {
    float4 a = L4[q];
    float4 b = L4[q + 25];
    s[4*q+0] = a.x + b.x;
    s[4*q+1] = a.y + b.y;
    s[4*q+2] = a.z + b.z;
    s[4*q+3] = a.w + b.w;
  }
  float pj0 = 0.0f, pj1 = 0.0f;
  #pragma unroll 1
  for (int r = 0; r < EPT; ++r) {
    int ep = k * EPT + r;
    if (EPT * SPLIT == E || ep < E) {
      float acc = 2.0f * bl[ep];
      dot25(s, (const float4*)(Wl + ep * E), acc);
      float o = fmaxf(acc, 0.0f);
      hdst[(size_t)node * E + ep] = o;
      pj0 = fmaf(o, Wp[ep], pj0);
      pj1 = fmaf(o, Wp[E + ep], pj1);
    }
  }
  #pragma unroll
  for (int d = SPLIT >> 1; d > 0; d >>= 1) {
    pj0 += __shfl_xor(pj0, d, 64);
    pj1 += __shfl_xor(pj1, d, 64);
  }
  if (k == 0) {
    int pos = ((node + 1) << (lvl + 1)) - 2 - __popc(node);
    out[2*pos]   = pj0 + bp[0];
    out[2*pos+1] = pj1 + bp[1];
  }
}

// Levels 12..17 (32 -> 1 nodes) in one block, LDS-resident ping-pong.
__global__ __launch_bounds__(512) void top_kernel(
    const float* __restrict__ h11,
    const float* __restrict__ Wl, const float* __restrict__ bl,
    const float* __restrict__ Wp, const float* __restrict__ bp,
    float* __restrict__ out) {
  __shared__ float bufA[64 * E];   // 25.6 KB
  __shared__ float bufB[32 * E];   // 12.8 KB
  const int tid = threadIdx.x;     // 512 threads
  for (int f = tid; f < 64 * E; f += 512) bufA[f] = h11[f];
  __syncthreads();
  float* c = bufA;
  float* x = bufB;
  int n = 32;
  for (int lvl = 12; lvl <= 17; ++lvl, n >>= 1) {
    int nn = tid >> 4;     // 16 lanes per node
    int k  = tid & 15;
    float pj0 = 0.0f, pj1 = 0.0f;
    if (nn < n) {
      float s[E];
      const float4* c4 = (const float4*)(c + nn * (2 * E));
      #pragma unroll
      for (int q = 0; q < 25; ++q) {
        float4 a = c4[q], b = c4[q + 25];
        s[4*q+0] = a.x + b.x;
        s[4*q+1] = a.y + b.y;
        s[4*q+2] = a.z + b.z;
        s[4*q+3] = a.w + b.w;
      }
      #pragma unroll 1
      for (int r = 0; r < 7; ++r) {
        int ep = k * 7 + r;      // 16*7 = 112 covers 100
        if (ep < E) {
          float acc = 2.0f * bl[ep];
          dot25(s, (const float4*)(Wl + ep * E), acc);
          float o = fmaxf(acc, 0.0f);
          x[nn * E + ep] = o;
          pj0 = fmaf(o, Wp[ep], pj0);
          pj1 = fmaf(o, Wp[E + ep], pj1);
        }
      }
    }
    #pragma unroll
    for (int d = 8; d > 0; d >>= 1) {
      pj0 += __shfl_xor(pj0, d, 64);
      pj1 += __shfl_xor(pj1, d, 64);
    }
    if (nn < n && k == 0) {
      int pos = ((nn + 1) << (lvl + 1)) - 2 - __popc(nn);
      out[2*pos]   = pj0 + bp[0];
      out[2*pos+1] = pj1 + bp[1];
    }
    __syncthreads();
    float* t = c; c = x; x = t;
  }
}

extern "C" void kernel_launch(void* const* d_in, const int* in_sizes, int n_in,
                              void* d_out, int out_size, void* d_ws, size_t ws_size,
                              hipStream_t stream) {
  const int*   word_ids = (const int*)  d_in[0];
  const float* emb      = (const float*)d_in[1];
  const float* Wl       = (const float*)d_in[2];
  const float* bl       = (const float*)d_in[3];
  const float* Wp       = (const float*)d_in[4];
  const float* bp       = (const float*)d_in[5];
  float* out = (float*)d_out;

  // ping-pong h buffers: odd levels (max 65536*100 floats), even levels (max 32768*100)
  float* hOdd  = (float*)d_ws;
  float* hEven = hOdd + (size_t)65536 * E;   // total ws use: 39.3 MB

  // level 0 (leaves) + level 1 fused
  leaf_l1_kernel<<<512, 256, 0, stream>>>(word_ids, emb, Wl, bl, Wp, bp, hOdd, out);

  const float* src = hOdd;
  for (int lvl = 2; lvl <= 11; ++lvl) {
    int n = 1 << (17 - lvl);
    float* dst = (lvl & 1) ? hOdd : hEven;
    int split = (lvl == 2) ? 2 : (lvl == 3 ? 4 : 8);
    int threads = n * split;
    int blocks = (threads + 255) / 256;
    if (split == 2) {
      combine_kernel<2><<<blocks, 256, 0, stream>>>(src, dst, Wl, bl, Wp, bp, out, n, lvl);
    } else if (split == 4) {
      combine_kernel<4><<<blocks, 256, 0, stream>>>(src, dst, Wl, bl, Wp, bp, out, n, lvl);
    } else {
      combine_kernel<8><<<blocks, 256, 0, stream>>>(src, dst, Wl, bl, Wp, bp, out, n, lvl);
    }
    src = dst;
  }

  // levels 12..17 in one block (src = level-11 buffer = hOdd)
  top_kernel<<<1, 512, 0, stream>>>(src, Wl, bl, Wp, bp, out);
}